// Round 15
// baseline (33.985 us; speedup 1.0000x reference)
//
#include <hip/hip_runtime.h>
#include <math.h>
#include <type_traits>

#define QDEPTH 10
#define WIRES 10
#define NSTATE 1024
#define NGATES (QDEPTH * WIRES)

typedef float f2 __attribute__((ext_vector_type(2)));
typedef float f4 __attribute__((ext_vector_type(4)));

// ---------------------------------------------------------------------------
// Final structure (r13, reverted from failed f16 r14): 1 wave = 1 element.
// Stored index s = j<<6|lane (j: 4 reg bits 9..6, lane: 6 bits 5..0).
// Wire q <-> bit (9-q):
//   bits 9..6 (wires 0-3): register gates (pure pk-FMA)
//   bit 5 (wire 4): permlane32_swap   bit 4 (wire 5): permlane16_swap
//   bit 3 (wire 6): DPP row_ror:8    bits 1,0 (wires 8,9): DPP quad_perm
//   bit 2 (wire 7): folded into the per-layer CNOT gather (one b128 read)
// LDS address: A(p) = ((p>>3)<<3)|((p&3)<<1)|bit2(p)  ({p,p^4} adjacent),
// bank-swizzled A~ = A ^ (((A>>6)&7)<<1). Zero per-layer barriers
// (wave-private LDS region); one staging barrier. Gate records computed
// in-kernel (fused). Per-layer coefficients batch-loaded into registers.
// f32 throughout (f16 fails absmax: 2.7e-2 > 2e-2, measured r14).
// ---------------------------------------------------------------------------
constexpr unsigned sigma_apply(int q, int r, unsigned i) {
    int cb = 9 - q, tb = 9 - ((q + r) % 10);
    return i ^ (((i >> cb) & 1u) << tb);
}
constexpr unsigned G_apply(int l, unsigned i) {
    int r = (l % 9) + 1;
    for (int q = 9; q >= 0; --q) i = sigma_apply(q, r, i);  // G = s0∘s1∘…∘s9
    return i;
}
constexpr unsigned Afun(unsigned p) {
    return ((p >> 3) << 3) | ((p & 3u) << 1) | ((p >> 2) & 1u);
}
constexpr unsigned Aswz(unsigned p) {
    unsigned a = Afun(p);
    return a ^ (((a >> 6) & 7u) << 1);
}

// entry = (A~(h&~4)>>1) | (bit2(h)<<15)
struct alignas(16) FoldT { unsigned short e[QDEPTH][64][16]; };   // 20 KB
constexpr FoldT make_fold() {
    FoldT t{};
    for (int l = 0; l < QDEPTH; ++l)
        for (unsigned lane = 0; lane < 64; ++lane)
            for (unsigned j = 0; j < 16; ++j) {
                unsigned s = (j << 6) | lane;
                unsigned h = G_apply(l, s);
                unsigned a = Aswz(h & ~4u);          // bit0 == 0 (swz keeps it)
                t.e[l][lane][j] =
                    (unsigned short)((a >> 1) | (((h >> 2) & 1u) << 15));
            }
    return t;
}
__constant__ FoldT FOLD = make_fold();

template <int N, int I = 0, typename F>
__device__ __forceinline__ void static_for(F&& f) {
    if constexpr (I < N) {
        f(std::integral_constant<int, I>{});
        static_for<N, I + 1>(f);
    }
}

__device__ __forceinline__ float fxor(float a, unsigned s) {
    return __uint_as_float(__float_as_uint(a) ^ s);
}
__device__ __forceinline__ f2 fxor2(f2 a, unsigned s) {
    f2 r; r.x = fxor(a.x, s); r.y = fxor(a.y, s); return r;
}
__device__ __forceinline__ f2 swap2(f2 a) { return __builtin_shufflevector(a, a, 1, 0); }
__device__ __forceinline__ f2 pkfma(f2 a, f2 b, f2 c) {
    return __builtin_elementwise_fma(a, b, c);
}

// Register gate on reg-bit JB of a 16-register state: 8 static pairs.
template <int JB>
__device__ __forceinline__ void apply_gate_reg(f2 (&s)[16], f2 ArP, f2 AiSW,
                                               f2 BrP, f2 BiSW) {
    static_for<8>([&](auto P) {
        constexpr int p  = P.value;
        constexpr int lo = p & ((1 << JB) - 1);
        constexpr int j  = ((p & ~((1 << JB) - 1)) << 1) | lo;
        constexpr int jp = j | (1 << JB);
        f2 a = s[j], b = s[jp];
        f2 as = swap2(a), bs = swap2(b);
        f2 n0 = a * ArP;
        n0 = pkfma(AiSW, as, n0); n0 = pkfma(BrP, b, n0); n0 = pkfma(BiSW, bs, n0);
        f2 n1 = a * (-BrP);
        n1 = pkfma(BiSW, as, n1); n1 = pkfma(ArP, b, n1); n1 = pkfma(-AiSW, bs, n1);
        s[j] = n0; s[jp] = n1;
    });
}

// Lane gate on bit 5 (xor32) / bit 4 (xor16) via permlane swap (r8-verified).
template <bool IS32>
__device__ __forceinline__ void plane_gate(f2& v, f2& w, f2 ArP, f2 AiSW,
                                           f2 BrP, f2 BiSW) {
    unsigned vx = __float_as_uint(v.x), vy = __float_as_uint(v.y);
    unsigned wx = __float_as_uint(w.x), wy = __float_as_uint(w.y);
    unsigned Xx, Xy, Yx, Yy;
    if constexpr (IS32) {
        auto rx = __builtin_amdgcn_permlane32_swap(vx, wx, false, false);
        auto ry = __builtin_amdgcn_permlane32_swap(vy, wy, false, false);
        Xx = rx[0]; Yx = rx[1]; Xy = ry[0]; Yy = ry[1];
    } else {
        auto rx = __builtin_amdgcn_permlane16_swap(vx, wx, false, false);
        auto ry = __builtin_amdgcn_permlane16_swap(vy, wy, false, false);
        Xx = rx[0]; Yx = rx[1]; Xy = ry[0]; Yy = ry[1];
    }
    f2 X, Y;
    X.x = __uint_as_float(Xx); X.y = __uint_as_float(Xy);
    Y.x = __uint_as_float(Yx); Y.y = __uint_as_float(Yy);
    f2 as = swap2(X), bs = swap2(Y);
    f2 n0 = X * ArP;
    n0 = pkfma(AiSW, as, n0); n0 = pkfma(BrP, Y, n0); n0 = pkfma(BiSW, bs, n0);
    f2 n1 = X * (-BrP);
    n1 = pkfma(BiSW, as, n1); n1 = pkfma(ArP, Y, n1); n1 = pkfma(-AiSW, bs, n1);
    unsigned ax = __float_as_uint(n0.x), ay = __float_as_uint(n0.y);
    unsigned bx = __float_as_uint(n1.x), by = __float_as_uint(n1.y);
    if constexpr (IS32) {
        auto ox = __builtin_amdgcn_permlane32_swap(ax, bx, false, false);
        auto oy = __builtin_amdgcn_permlane32_swap(ay, by, false, false);
        v.x = __uint_as_float(ox[0]); v.y = __uint_as_float(oy[0]);
        w.x = __uint_as_float(ox[1]); w.y = __uint_as_float(oy[1]);
    } else {
        auto ox = __builtin_amdgcn_permlane16_swap(ax, bx, false, false);
        auto oy = __builtin_amdgcn_permlane16_swap(ay, by, false, false);
        v.x = __uint_as_float(ox[0]); v.y = __uint_as_float(oy[0]);
        w.x = __uint_as_float(ox[1]); w.y = __uint_as_float(oy[1]);
    }
}

template <int CTRL>
__device__ __forceinline__ f2 dpp2(f2 v) {
    f2 r;
    r.x = __uint_as_float((unsigned)__builtin_amdgcn_mov_dpp(
              (int)__float_as_uint(v.x), CTRL, 0xf, 0xf, true));
    r.y = __uint_as_float((unsigned)__builtin_amdgcn_mov_dpp(
              (int)__float_as_uint(v.y), CTRL, 0xf, 0xf, true));
    return r;
}

// Lane gate via DPP partner + per-lane signs (r8-verified).
template <int CTRL, int M>
__device__ __forceinline__ void dpp_gate(f2 (&s)[16], int lane, f2 ArP, f2 AiSW,
                                         f2 BrP, f2 BiSW) {
    const unsigned sm = (lane & M) ? 0x80000000u : 0u;
    const f2 c2 = fxor2(AiSW, sm);
    const f2 c3 = fxor2(BrP, sm);
    static_for<16>([&](auto J) {
        constexpr int j = J.value;
        f2 a = s[j];
        f2 p = dpp2<CTRL>(a);
        f2 n = a * ArP;
        n = pkfma(c2, swap2(a), n);
        n = pkfma(c3, p, n);
        n = pkfma(BiSW, swap2(p), n);
        s[j] = n;
    });
}

// ---------------------------------------------------------------------------
// Fused kernel: 256 blocks x 256 thr = 1024 waves; 1 wave = 1 element;
// 16 f2 amps/thread. Gate records computed in-prologue (threads 0..99).
// Zero per-layer barriers; coefficients batch-loaded to regs per layer.
// ---------------------------------------------------------------------------
__global__ __launch_bounds__(256, 1) void sim_kernel(const float* __restrict__ x,
                                                     const float* __restrict__ wts,
                                                     float* __restrict__ out) {
    __shared__ f2 amps[4][NSTATE];       // per-wave private regions, 32 KB
    __shared__ f2 glds[NGATES * 4];      // packed gate records, 3.2 KB
    const int tid  = threadIdx.x;
    const int w    = tid >> 6;
    const int lane = tid & 63;
    const int elem = blockIdx.x * 4 + w;
    const float* xb = x + (size_t)elem * NSTATE;
    f2* myb = amps[w];

    f2 s[16];

    // ---- issue amplitude loads first (HBM latency hides under gate math) ----
    float v[16];
    static_for<16>([&](auto J) {
        constexpr int j = J.value;
        v[j] = xb[(j << 6) | lane];
    });

    // ---- fused gate computation: thread i<100 -> gate i records ----
    if (tid < NGATES) {
        float phi = tanhf(wts[3 * tid + 0]);
        float th  = tanhf(wts[3 * tid + 1]);
        float om  = tanhf(wts[3 * tid + 2]);
        float c = cosf(0.5f * th), sn = sinf(0.5f * th);
        float a = 0.5f * (phi + om), d = 0.5f * (phi - om);
        float Ar =  cosf(a) * c, Ai = -sinf(a) * c;    // g00
        float Br = -cosf(d) * sn, Bi = -sinf(d) * sn;  // g01
        f2 r0; r0.x = Ar;  r0.y = Ar;
        f2 r1; r1.x = -Ai; r1.y = Ai;
        f2 r2; r2.x = Br;  r2.y = Br;
        f2 r3; r3.x = -Bi; r3.y = Bi;
        glds[4 * tid + 0] = r0;
        glds[4 * tid + 1] = r1;
        glds[4 * tid + 2] = r2;
        glds[4 * tid + 3] = r3;
    }

    // ---- per-wave L2 normalize ----
    float ss = 0.f;
    static_for<16>([&](auto J) {
        constexpr int j = J.value;
        s[j].x = v[j]; s[j].y = 0.f;
        ss = fmaf(v[j], v[j], ss);
    });
#pragma unroll
    for (int off = 1; off < 64; off <<= 1) ss += __shfl_xor(ss, off);
    const float nrm = 1.0f / sqrtf(ss);
    static_for<16>([&](auto J) { s[J.value] *= nrm; });

    __syncthreads();                     // glds ready (only barrier)

    // write-address lane base of A~ (j-part of swizzle applied per j)
    const int wb = ((lane >> 3) << 3) | ((lane & 3) << 1) | ((lane >> 2) & 1);

    // prefetch layer-0 fold entries (32 B, coalesced)
    uint4 fa = *(const uint4*)&FOLD.e[0][lane][0];
    uint4 fb = *(const uint4*)&FOLD.e[0][lane][8];

#pragma unroll 1
    for (int l = 0; l < QDEPTH; ++l) {
        const f2* gl = glds + 40 * l;
        unsigned ew[8] = { fa.x, fa.y, fa.z, fa.w, fb.x, fb.y, fb.z, fb.w };

        // ---- batch-load ALL 40 coefficient f2s for this layer into regs ----
        f2 gr[40];
        static_for<40>([&](auto I_) {
            constexpr int i = I_.value;
            gr[i] = gl[i];
        });

        // prefetch next layer's fold entries (hidden under gate compute)
        if (l < QDEPTH - 1) {
            fa = *(const uint4*)&FOLD.e[l + 1][lane][0];
            fb = *(const uint4*)&FOLD.e[l + 1][lane][8];
        }

        // ---- wires 0..3 on reg bits 9..6 ----
        apply_gate_reg<3>(s, gr[0],  gr[1],  gr[2],  gr[3]);
        apply_gate_reg<2>(s, gr[4],  gr[5],  gr[6],  gr[7]);
        apply_gate_reg<1>(s, gr[8],  gr[9],  gr[10], gr[11]);
        apply_gate_reg<0>(s, gr[12], gr[13], gr[14], gr[15]);

        // ---- wire 4 (bit 5, xor32) / wire 5 (bit 4, xor16) via permlane ----
        static_for<8>([&](auto K) {
            constexpr int k = K.value;
            plane_gate<true>(s[2 * k], s[2 * k + 1], gr[16], gr[17], gr[18], gr[19]);
        });
        static_for<8>([&](auto K) {
            constexpr int k = K.value;
            plane_gate<false>(s[2 * k], s[2 * k + 1], gr[20], gr[21], gr[22], gr[23]);
        });

        // ---- wire 6 (bit 3, row_ror:8); wires 8,9 (quad_perm) ----
        dpp_gate<0x128, 8>(s, lane, gr[24], gr[25], gr[26], gr[27]);
        dpp_gate<0x04E, 2>(s, lane, gr[32], gr[33], gr[34], gr[35]);
        dpp_gate<0x0B1, 1>(s, lane, gr[36], gr[37], gr[38], gr[39]);

        // ---- write state to swizzled A~-layout (wave-private, no barrier) ----
        static_for<16>([&](auto J) {
            constexpr int j = J.value;
            myb[(j << 6) | (wb ^ ((j & 7) << 1))] = s[j];
        });

        // ---- wire 7 (bit 2) folded into CNOT gather: one b128 per amp ----
        {
            const f2 ArP = gr[28], AiSW = gr[29], BrP = gr[30], BiSW = gr[31];
            static_for<16>([&](auto J) {
                constexpr int j = J.value;
                unsigned e16 = (j & 1) ? (ew[j >> 1] >> 16) : (ew[j >> 1] & 0xFFFFu);
                unsigned sm  = (e16 & 0x8000u) << 16;       // h2 -> sign bit
                const f4 pv = *(const f4*)&myb[(e16 & 0x1FFu) << 1];
                f2 v0; v0.x = pv.x; v0.y = pv.y;            // bit2 = 0 source
                f2 v1; v1.x = pv.z; v1.y = pv.w;            // bit2 = 1 source
                bool h2 = (e16 & 0x8000u) != 0;
                f2 a  = h2 ? v1 : v0;                       // self
                f2 pp = h2 ? v0 : v1;                       // partner
                f2 c2 = fxor2(AiSW, sm);
                f2 c3 = fxor2(BrP, sm);
                f2 n = a * ArP;
                n = pkfma(c2, swap2(a), n);
                n = pkfma(c3, pp, n);
                n = pkfma(BiSW, swap2(pp), n);
                s[j] = n;
            });
        }
    }

    // ---- probs = clip(|amp|^2 * 1024, 0, 1); identity layout ----
    float* ob = out + (size_t)elem * NSTATE;
    static_for<16>([&](auto J) {
        constexpr int j = J.value;
        float p = fmaf(s[j].x, s[j].x, s[j].y * s[j].y) * (float)NSTATE;
        ob[(j << 6) | lane] = fminf(p, 1.0f);
    });
}

extern "C" void kernel_launch(void* const* d_in, const int* in_sizes, int n_in,
                              void* d_out, int out_size, void* d_ws, size_t ws_size,
                              hipStream_t stream) {
    const float* x = (const float*)d_in[0];   // [1024,1,32,32] f32
    const float* w = (const float*)d_in[1];   // [10,10,3] f32
    float* out = (float*)d_out;               // [1024,1,32,32] f32

    sim_kernel<<<256, 256, 0, stream>>>(x, w, out);
}